// Round 3
// baseline (874.358 us; speedup 1.0000x reference)
//
#include <hip/hip_runtime.h>
#include <stdint.h>

#define NCLS 80
#define NKER 256
#define STOT 3872
#define NFLAT (STOT*NCLS)   // 309760
#define NPRE 500
#define NPREP 512
#define MAXI 100
#define MH 160
#define MW 240
#define MP (MH*MW)          // 38400
#define OH 640
#define OW 960
#define NWORD 600           // 38400/64

// ---- workspace byte offsets (8B aligned) ----
#define WS_HIST   0u          // 65536 u32
#define WS_META   262144u
#define WS_IOU    266240u     // 500*500 f64 = 2,000,000
#define WS_ZEROB  2266240u    // memset range
#define WS_FLAT   2266240u    // 309760 f64
#define WS_CANDV  4744320u    // 4096 f64
#define WS_CANDI  4777088u    // 4096 i32
#define WS_SEL    4793472u    // small arrays
#define WS_KPT    4859008u    // 256*512 f32
#define WS_MB     5383296u    // 500*600 u64
#define WS_PART   7783296u    // 500*600 f64
#define WS_SEG    10183296u   // 500*38400 u16 (bf16) -> ends ~48.6MB

__device__ __forceinline__ double sigd(float x) { return 1.0 / (1.0 + exp(-(double)x)); }
__device__ __forceinline__ float bf2f(unsigned short u) { return __uint_as_float(((unsigned)u) << 16); }
__device__ __forceinline__ unsigned short f2bf(float f) {
  unsigned b = __float_as_uint(f);
  return (unsigned short)((b + 0x7fffu + ((b >> 16) & 1u)) >> 16);
}

// ---------- K1: fp64 sigmoid + point-NMS + threshold -> flat (f64) + f32-bucket histogram ----------
__global__ __launch_bounds__(256) void k_flat(
    const float* __restrict__ c0, const float* __restrict__ c1, const float* __restrict__ c2,
    const float* __restrict__ c3, const float* __restrict__ c4,
    double* __restrict__ flat, unsigned* __restrict__ hist) {
  int idx = blockIdx.x * 256 + threadIdx.x;
  if (idx >= NFLAT) return;
  int s = idx / NCLS, c = idx - s * NCLS;
  const float* base; int g, cell;
  if (s < 1600)      { base = c0; g = 40; cell = s; }
  else if (s < 2896) { base = c1; g = 36; cell = s - 1600; }
  else if (s < 3472) { base = c2; g = 24; cell = s - 2896; }
  else if (s < 3728) { base = c3; g = 16; cell = s - 3472; }
  else               { base = c4; g = 12; cell = s - 3728; }
  int i = cell / g, j = cell - i * g;
  const float* ch = base + c * g * g;
  double sv = sigd(ch[i * g + j]);
  double mx = sv;
  if (i > 0 && j > 0) mx = fmax(mx, sigd(ch[(i - 1) * g + j - 1]));
  if (i > 0)          mx = fmax(mx, sigd(ch[(i - 1) * g + j]));
  if (j > 0)          mx = fmax(mx, sigd(ch[i * g + j - 1]));
  double v = (sv == mx && sv > 0.1) ? sv : 0.0;
  flat[idx] = v;
  if (v > 0.0) atomicAdd(&hist[__float_as_uint((float)v) >> 16], 1u);
}

// ---------- K2: pivot bucket so that count(>= pivot) >= 500 ----------
__global__ void k_pivot(const unsigned* __restrict__ hist, unsigned* __restrict__ meta) {
  __shared__ unsigned csum[1024];
  int t = threadIdx.x;
  int hi = 65536 - t * 64, lo = hi - 64;
  unsigned s = 0;
  for (int b = lo; b < hi; ++b) s += hist[b];
  csum[t] = s;
  __syncthreads();
  if (t == 0) {
    unsigned cum = 0;
    for (int cch = 0; cch < 1024; ++cch) {
      if (cum + csum[cch] >= NPRE) {
        int chi = 65536 - cch * 64;
        for (int b = chi - 1; b >= chi - 64; --b) {
          if (cum + hist[b] >= NPRE) { meta[1] = (unsigned)b; return; }
          cum += hist[b];
        }
      }
      cum += csum[cch];
    }
    meta[1] = 1u;
  }
}

// ---------- K3: compact candidates (value f64, index) ----------
__global__ __launch_bounds__(256) void k_compact(
    const double* __restrict__ flat, double* __restrict__ cv, int* __restrict__ ci,
    unsigned* __restrict__ meta) {
  int idx = blockIdx.x * 256 + threadIdx.x;
  if (idx >= NFLAT) return;
  double v = flat[idx];
  if (v <= 0.0) return;
  if ((__float_as_uint((float)v) >> 16) >= meta[1]) {
    unsigned pos = atomicAdd(&meta[0], 1u);
    if (pos < 4096u) { cv[pos] = v; ci[pos] = idx; }
  }
}

// ---------- K4: exact (f64,idx) bitonic sort of candidates, take top-500 ----------
__global__ __launch_bounds__(1024) void k_select(
    const double* __restrict__ cv, const int* __restrict__ ci, const unsigned* __restrict__ meta,
    double* __restrict__ sel_score, unsigned* __restrict__ sel_grid,
    unsigned* __restrict__ sel_label, double* __restrict__ sel_stride) {
  __shared__ double sv[4096];
  __shared__ int si[4096];
  int t = threadIdx.x;
  int n = (meta[0] < 4096u) ? (int)meta[0] : 4096;
  for (int i = t; i < 4096; i += 1024) {
    if (i < n) { sv[i] = cv[i]; si[i] = ci[i]; }
    else       { sv[i] = -1.0;  si[i] = (1 << 30) + i; }
  }
  __syncthreads();
  for (int k = 2; k <= 4096; k <<= 1)
    for (int j = k >> 1; j > 0; j >>= 1) {
      for (int i = t; i < 4096; i += 1024) {
        int ix = i ^ j;
        if (ix > i) {
          double v1 = sv[i], v2 = sv[ix]; int i1 = si[i], i2 = si[ix];
          bool b2 = (v2 > v1) || (v2 == v1 && i2 < i1);  // entry ix ranks before entry i
          bool dir = (i & k) == 0;
          if (dir == b2) { sv[i] = v2; sv[ix] = v1; si[i] = i2; si[ix] = i1; }
        }
      }
      __syncthreads();
    }
  for (int i = t; i < NPREP; i += 1024) {
    if (i < NPRE && i < n) {
      int fidx = si[i];
      unsigned gi = (unsigned)fidx / NCLS;
      sel_score[i] = sv[i];
      sel_grid[i] = gi;
      sel_label[i] = (unsigned)fidx - gi * NCLS;
      sel_stride[i] = gi < 2896u ? 8.0 : (gi < 3472u ? 16.0 : 32.0);
    } else {
      sel_score[i] = 0.0; sel_grid[i] = 0u; sel_label[i] = 0u; sel_stride[i] = 1e18;
    }
  }
}

// ---------- K5: gather kernel vectors transposed kpT[k][n] ----------
__global__ __launch_bounds__(256) void k_gather(
    const float* __restrict__ k0, const float* __restrict__ k1, const float* __restrict__ k2,
    const float* __restrict__ k3, const float* __restrict__ k4,
    const unsigned* __restrict__ sel_grid, float* __restrict__ kpT) {
  int tid = blockIdx.x * 256 + threadIdx.x;
  if (tid >= NPREP * NKER) return;
  int n = tid & (NPREP - 1);
  int k = tid >> 9;
  float v = 0.f;
  if (n < NPRE) {
    unsigned gi = sel_grid[n];
    const float* base; unsigned g, cell;
    if (gi < 1600u)      { base = k0; g = 40; cell = gi; }
    else if (gi < 2896u) { base = k1; g = 36; cell = gi - 1600u; }
    else if (gi < 3472u) { base = k2; g = 24; cell = gi - 2896u; }
    else if (gi < 3728u) { base = k3; g = 16; cell = gi - 3472u; }
    else                 { base = k4; g = 12; cell = gi - 3728u; }
    v = base[(unsigned)k * g * g + cell];
  }
  kpT[k * NPREP + n] = v;
}

// ---------- K6: fp64 GEMM + sigmoid + mask bits + masked partial sums + bf16 seg store ----------
__global__ __launch_bounds__(256) void k_gemm(
    const float* __restrict__ kpT, const float* __restrict__ mf,
    unsigned short* __restrict__ seg, unsigned long long* __restrict__ mb,
    double* __restrict__ part) {
  __shared__ double smem[8192];                       // 64KB
  double (*As)[64] = (double(*)[64])smem;             // [k][n]
  double (*Bs)[64] = (double(*)[64])(smem + 4096);    // [k][p]
  int p0 = blockIdx.x * 64, n0 = blockIdx.y * 64;
  int tid = threadIdx.x;
  int tp = tid & 15, tn = tid >> 4;
  double acc[4][4] = {};
  for (int kc = 0; kc < NKER; kc += 64) {
    for (int q = tid; q < 1024; q += 256) {
      int row = q >> 4, c4 = (q & 15) << 2;
      float4 a4 = *(const float4*)&kpT[(kc + row) * NPREP + n0 + c4];
      float4 b4 = *(const float4*)&mf[(size_t)(kc + row) * MP + p0 + c4];
      As[row][c4] = (double)a4.x; As[row][c4+1] = (double)a4.y;
      As[row][c4+2] = (double)a4.z; As[row][c4+3] = (double)a4.w;
      Bs[row][c4] = (double)b4.x; Bs[row][c4+1] = (double)b4.y;
      Bs[row][c4+2] = (double)b4.z; Bs[row][c4+3] = (double)b4.w;
    }
    __syncthreads();
#pragma unroll 8
    for (int k = 0; k < 64; ++k) {
      double a0 = As[k][(tn<<2)+0], a1 = As[k][(tn<<2)+1], a2 = As[k][(tn<<2)+2], a3 = As[k][(tn<<2)+3];
      double b0 = Bs[k][(tp<<2)+0], b1 = Bs[k][(tp<<2)+1], b2 = Bs[k][(tp<<2)+2], b3 = Bs[k][(tp<<2)+3];
      acc[0][0] = fma(a0,b0,acc[0][0]); acc[0][1] = fma(a0,b1,acc[0][1]);
      acc[0][2] = fma(a0,b2,acc[0][2]); acc[0][3] = fma(a0,b3,acc[0][3]);
      acc[1][0] = fma(a1,b0,acc[1][0]); acc[1][1] = fma(a1,b1,acc[1][1]);
      acc[1][2] = fma(a1,b2,acc[1][2]); acc[1][3] = fma(a1,b3,acc[1][3]);
      acc[2][0] = fma(a2,b0,acc[2][0]); acc[2][1] = fma(a2,b1,acc[2][1]);
      acc[2][2] = fma(a2,b2,acc[2][2]); acc[2][3] = fma(a2,b3,acc[2][3]);
      acc[3][0] = fma(a3,b0,acc[3][0]); acc[3][1] = fma(a3,b1,acc[3][1]);
      acc[3][2] = fma(a3,b2,acc[3][2]); acc[3][3] = fma(a3,b3,acc[3][3]);
    }
    __syncthreads();
  }
  // epilogue: fp64 sigmoid, mask bits, masked sum, bf16 store
  unsigned nibv[4]; double wsv[4];
  for (int r = 0; r < 4; ++r) {
    int nn = n0 + (tn << 2) + r;
    unsigned nb = 0; double ws = 0.0;
    unsigned short u[4];
    for (int c = 0; c < 4; ++c) {
      double s = 1.0 / (1.0 + exp(-acc[r][c]));
      u[c] = f2bf((float)s);
      if (s > 0.5) { nb |= 1u << c; ws += s; }
    }
    if (nn < NPRE) {
      ushort4 o; o.x = u[0]; o.y = u[1]; o.z = u[2]; o.w = u[3];
      *(ushort4*)&seg[(size_t)nn * MP + p0 + (tp << 2)] = o;
    }
    nibv[r] = nb; wsv[r] = ws;
  }
  // overlay stats in (now dead) LDS
  double* partL = smem;                       // [64][16]
  unsigned* nibL = (unsigned*)(smem + 1024);  // [64][16]
  for (int r = 0; r < 4; ++r) {
    int nl = (tn << 2) + r;
    partL[nl * 16 + tp] = wsv[r];
    nibL[nl * 16 + tp] = nibv[r];
  }
  __syncthreads();
  if (tid < 64) {
    int nn = n0 + tid;
    if (nn < NPRE) {
      double s = 0.0; unsigned long long w = 0ull;
      for (int c = 0; c < 16; ++c) {
        s += partL[tid * 16 + c];
        w |= ((unsigned long long)nibL[tid * 16 + c]) << (c << 2);
      }
      part[nn * NWORD + blockIdx.x] = s;
      mb[nn * NWORD + blockIdx.x] = w;
    }
  }
}

// ---------- K7: per-instance reduce (exact count + fp64 weighted sum) -> updated score ----------
__global__ void k_masks(const unsigned long long* __restrict__ mb, const double* __restrict__ part,
                        const double* __restrict__ sel_score, const double* __restrict__ sel_stride,
                        double* __restrict__ summask, double* __restrict__ upd) {
  int n = blockIdx.x, t = threadIdx.x;
  int cnt = 0; double ws = 0.0;
  for (int j = t; j < NWORD; j += 64) { cnt += __popcll(mb[n * NWORD + j]); ws += part[n * NWORD + j]; }
  for (int o = 32; o > 0; o >>= 1) { cnt += __shfl_down(cnt, o); ws += __shfl_down(ws, o); }
  if (t == 0) {
    double cf = (double)cnt;
    double ss = ws / fmax(cf, 1.0);
    double raw = sel_score[n];
    bool keep = (cf > sel_stride[n]) && (raw > 0.0);
    summask[n] = cf;
    upd[n] = keep ? raw * ss : 0.0;
  }
}

// ---------- K8: stable descending fp64 sort of updated scores ----------
__global__ __launch_bounds__(512) void k_sort(
    const double* __restrict__ upd, const unsigned* __restrict__ sel_label, const double* __restrict__ summask,
    double* __restrict__ s_score, unsigned* __restrict__ s_slot, unsigned* __restrict__ s_label2,
    double* __restrict__ s_sum, unsigned* __restrict__ s_alive) {
  __shared__ double sv[NPREP];
  __shared__ int si[NPREP];
  int t = threadIdx.x;
  sv[t] = (t < NPRE) ? upd[t] : -1.0;
  si[t] = t;
  __syncthreads();
  for (int k = 2; k <= NPREP; k <<= 1)
    for (int j = k >> 1; j > 0; j >>= 1) {
      int ix = t ^ j;
      if (ix > t) {
        double v1 = sv[t], v2 = sv[ix]; int i1 = si[t], i2 = si[ix];
        bool b2 = (v2 > v1) || (v2 == v1 && i2 < i1);
        bool dir = (t & k) == 0;
        if (dir == b2) { sv[t] = v2; sv[ix] = v1; si[t] = i2; si[ix] = i1; }
      }
      __syncthreads();
    }
  double sc = sv[t]; int slot = si[t];
  bool alive = sc > 0.0;
  s_score[t] = alive ? sc : 0.0;
  s_slot[t] = (unsigned)slot;
  s_label2[t] = sel_label[slot];
  s_sum[t] = (alive && slot < NPRE) ? summask[slot] : 0.0;
  s_alive[t] = alive ? 1u : 0u;
}

// ---------- K9: pairwise IoU via popcount (exact), fp64 ----------
__global__ __launch_bounds__(256) void k_inter(
    const unsigned long long* __restrict__ mb, const unsigned* __restrict__ s_slot,
    const unsigned* __restrict__ s_label2, const unsigned* __restrict__ s_alive,
    const double* __restrict__ s_sum, double* __restrict__ iou) {
  int w = (blockIdx.x * 256 + threadIdx.x) >> 6;
  int lane = threadIdx.x & 63;
  if (w >= NPRE * NPRE) return;
  int i = w / NPRE, j = w - i * NPRE;
  if (i >= j) return;
  if (s_label2[i] != s_label2[j] || !s_alive[i] || !s_alive[j]) return;
  const unsigned long long* A = mb + (size_t)s_slot[i] * NWORD;
  const unsigned long long* B = mb + (size_t)s_slot[j] * NWORD;
  int c = 0;
  for (int wd = lane; wd < NWORD; wd += 64) c += __popcll(A[wd] & B[wd]);
  for (int o = 32; o > 0; o >>= 1) c += __shfl_down(c, o);
  if (lane == 0) {
    double inter = (double)c;
    double uni = s_sum[i] + s_sum[j] - inter;
    iou[i * NPRE + j] = (uni > 0.0) ? inter / fmax(uni, 1.0) : 0.0;
  }
}

// ---------- K10: matrix-NMS decay (fp64) + 0.05 threshold ----------
__global__ __launch_bounds__(512) void k_nms(const double* __restrict__ iou,
                                             const double* __restrict__ s_score,
                                             double* __restrict__ final_) {
  __shared__ double compS[NPREP];
  int t = threadIdx.x;
  double cm = 0.0;
  if (t < NPRE)
    for (int i = 0; i < t; ++i) cm = fmax(cm, iou[i * NPRE + t]);
  compS[t] = cm;
  __syncthreads();
  if (t < NPRE) {
    double m = 0.0;
    for (int i = 0; i < t; ++i) {
      double d = iou[i * NPRE + t];
      m = fmax(m, d * d - compS[i] * compS[i]);
    }
    double f = s_score[t] * exp(-2.0 * m);
    final_[t] = (f >= 0.05) ? f : 0.0;
  } else {
    final_[t] = 0.0;
  }
}

// ---------- K11: final stable top-100 ----------
__global__ __launch_bounds__(512) void k_top100(
    const double* __restrict__ final_, const unsigned* __restrict__ s_label2,
    const unsigned* __restrict__ s_slot, float* __restrict__ d_out, int maskN,
    unsigned* __restrict__ up_slot) {
  __shared__ double sv[NPREP];
  __shared__ int si[NPREP];
  int t = threadIdx.x;
  sv[t] = final_[t]; si[t] = t;
  __syncthreads();
  for (int k = 2; k <= NPREP; k <<= 1)
    for (int j = k >> 1; j > 0; j >>= 1) {
      int ix = t ^ j;
      if (ix > t) {
        double v1 = sv[t], v2 = sv[ix]; int i1 = si[t], i2 = si[ix];
        bool b2 = (v2 > v1) || (v2 == v1 && i2 < i1);
        bool dir = (t & k) == 0;
        if (dir == b2) { sv[t] = v2; sv[ix] = v1; si[t] = i2; si[ix] = i1; }
      }
      __syncthreads();
    }
  if (t < MAXI) {
    int pos = si[t];
    d_out[maskN + t] = (float)sv[t];
    d_out[maskN + MAXI + t] = (float)s_label2[pos];
    up_slot[t] = s_slot[pos];
  }
}

// ---------- K12: 4x bilinear upsample (bf16 seg) + threshold ----------
__global__ __launch_bounds__(256) void k_up(const unsigned short* __restrict__ seg,
                                            const unsigned* __restrict__ up_slot,
                                            float* __restrict__ out, int maskN) {
  int o = blockIdx.x * 256 + threadIdx.x;
  if (o >= maskN) return;
  int m = o / (OH * OW);
  int rem = o - m * (OH * OW);
  int y = rem / OW, x = rem - y * OW;
  const unsigned short* row = seg + (size_t)up_slot[m] * MP;
  float sy = y * 0.25f - 0.375f, sx = x * 0.25f - 0.375f;
  int y0 = (int)floorf(sy), x0 = (int)floorf(sx);
  float wy = sy - y0, wx = sx - x0;
  int y0c = max(y0, 0), y1c = min(y0 + 1, MH - 1);
  int x0c = max(x0, 0), x1c = min(x0 + 1, MW - 1);
  float s00 = bf2f(row[y0c * MW + x0c]), s01 = bf2f(row[y0c * MW + x1c]);
  float s10 = bf2f(row[y1c * MW + x0c]), s11 = bf2f(row[y1c * MW + x1c]);
  float v = (1.f - wy) * ((1.f - wx) * s00 + wx * s01) + wy * ((1.f - wx) * s10 + wx * s11);
  out[o] = (v > 0.5f) ? 1.f : 0.f;
}

extern "C" void kernel_launch(void* const* d_in, const int* in_sizes, int n_in,
                              void* d_out, int out_size, void* d_ws, size_t ws_size,
                              hipStream_t stream) {
  // setup_inputs() dict order is INTERLEAVED: cate_p0, kern_p0, cate_p1, kern_p1, ...
  const float* c0 = (const float*)d_in[0];
  const float* k0 = (const float*)d_in[1];
  const float* c1 = (const float*)d_in[2];
  const float* k1 = (const float*)d_in[3];
  const float* c2 = (const float*)d_in[4];
  const float* k2 = (const float*)d_in[5];
  const float* c3 = (const float*)d_in[6];
  const float* k3 = (const float*)d_in[7];
  const float* c4 = (const float*)d_in[8];
  const float* k4 = (const float*)d_in[9];
  const float* mf = (const float*)d_in[10];

  char* ws = (char*)d_ws;
  unsigned* hist = (unsigned*)(ws + WS_HIST);
  unsigned* meta = (unsigned*)(ws + WS_META);
  double* iou = (double*)(ws + WS_IOU);
  double* flat = (double*)(ws + WS_FLAT);
  double* cv = (double*)(ws + WS_CANDV);
  int* ci = (int*)(ws + WS_CANDI);
  double* sel_score  = (double*)(ws + WS_SEL + 0);
  unsigned* sel_grid = (unsigned*)(ws + WS_SEL + 4096);
  unsigned* sel_label= (unsigned*)(ws + WS_SEL + 8192);
  double* sel_stride = (double*)(ws + WS_SEL + 12288);
  double* upd        = (double*)(ws + WS_SEL + 16384);
  double* summask    = (double*)(ws + WS_SEL + 20480);
  double* s_score    = (double*)(ws + WS_SEL + 24576);
  unsigned* s_slot   = (unsigned*)(ws + WS_SEL + 28672);
  unsigned* s_label2 = (unsigned*)(ws + WS_SEL + 32768);
  double* s_sum      = (double*)(ws + WS_SEL + 36864);
  unsigned* s_alive  = (unsigned*)(ws + WS_SEL + 40960);
  double* final_     = (double*)(ws + WS_SEL + 45056);
  unsigned* up_slot  = (unsigned*)(ws + WS_SEL + 49152);
  float* kpT = (float*)(ws + WS_KPT);
  unsigned long long* mb = (unsigned long long*)(ws + WS_MB);
  double* part = (double*)(ws + WS_PART);
  unsigned short* seg = (unsigned short*)(ws + WS_SEG);

  int maskN = out_size - 2 * MAXI;  // 100*640*960

  hipMemsetAsync(ws, 0, WS_ZEROB, stream);  // hist + meta + iou

  k_flat<<<(NFLAT + 255) / 256, 256, 0, stream>>>(c0, c1, c2, c3, c4, flat, hist);
  k_pivot<<<1, 1024, 0, stream>>>(hist, meta);
  k_compact<<<(NFLAT + 255) / 256, 256, 0, stream>>>(flat, cv, ci, meta);
  k_select<<<1, 1024, 0, stream>>>(cv, ci, meta, sel_score, sel_grid, sel_label, sel_stride);
  k_gather<<<(NPREP * NKER + 255) / 256, 256, 0, stream>>>(k0, k1, k2, k3, k4, sel_grid, kpT);
  dim3 g6(MP / 64, NPREP / 64);
  k_gemm<<<g6, 256, 0, stream>>>(kpT, mf, seg, mb, part);
  k_masks<<<NPRE, 64, 0, stream>>>(mb, part, sel_score, sel_stride, summask, upd);
  k_sort<<<1, NPREP, 0, stream>>>(upd, sel_label, summask, s_score, s_slot, s_label2, s_sum, s_alive);
  k_inter<<<(NPRE * NPRE) / 4, 256, 0, stream>>>(mb, s_slot, s_label2, s_alive, s_sum, iou);
  k_nms<<<1, NPREP, 0, stream>>>(iou, s_score, final_);
  k_top100<<<1, NPREP, 0, stream>>>(final_, s_label2, s_slot, (float*)d_out, maskN, up_slot);
  k_up<<<(maskN + 255) / 256, 256, 0, stream>>>(seg, up_slot, (float*)d_out, maskN);
}

// Round 4
// 724.628 us; speedup vs baseline: 1.2066x; 1.2066x over previous
//
#include <hip/hip_runtime.h>
#include <stdint.h>

#define NCLS 80
#define NKER 256
#define STOT 3872
#define NFLAT (STOT*NCLS)   // 309760
#define NPRE 500
#define NPREP 512
#define MAXI 100
#define MH 160
#define MW 240
#define MP (MH*MW)          // 38400
#define OH 640
#define OW 960
#define NWORD 600           // 38400/64
#define PARTW 300           // 38400/128

// GEMM tiling
#define BN 64
#define BP 128
#define BK 64

// ---- workspace byte offsets ----
#define WS_HIST   0u          // 65536 u32 = 262144
#define WS_META   262144u
#define WS_IOU    266240u     // 500*500 f64 = 2,000,000
#define WS_ZEROB  2266240u    // memset range [0, WS_ZEROB)
#define WS_FLAT   2266240u    // 309760 f32 = 1,239,040
#define WS_CANDV  3505280u    // 4096 f32
#define WS_CANDI  3521664u    // 4096 i32
#define WS_SEL    3538048u    // 13 arrays x 4096B
#define WS_KPT    3591296u    // 256*512 f32 = 524,288
#define WS_MB     4115584u    // 500*600 u64 = 2,400,000
#define WS_PART   6515584u    // 500*300 f64 = 1,200,000
#define WS_SEG    7715584u    // 500*38400 u16 (bf16) -> ends ~46.1MB

__device__ __forceinline__ float bf2f(unsigned short u) { return __uint_as_float(((unsigned)u) << 16); }
__device__ __forceinline__ unsigned short f2bf(float f) {
  unsigned b = __float_as_uint(f);
  return (unsigned short)((b + 0x7fffu + ((b >> 16) & 1u)) >> 16);
}
// monotone float->uint key (total order matching <)
__device__ __forceinline__ unsigned fkey(float f) {
  unsigned b = __float_as_uint(f);
  return b ^ ((b & 0x80000000u) ? 0xFFFFFFFFu : 0x80000000u);
}

// ---------- K1: point-NMS + threshold in LOGIT space (exact-equivalent, no exp) ----------
__global__ __launch_bounds__(256) void k_flat(
    const float* __restrict__ c0, const float* __restrict__ c1, const float* __restrict__ c2,
    const float* __restrict__ c3, const float* __restrict__ c4,
    float* __restrict__ flat, unsigned* __restrict__ hist) {
  int idx = blockIdx.x * 256 + threadIdx.x;
  if (idx >= NFLAT) return;
  int s = idx / NCLS, c = idx - s * NCLS;
  const float* base; int g, cell;
  if (s < 1600)      { base = c0; g = 40; cell = s; }
  else if (s < 2896) { base = c1; g = 36; cell = s - 1600; }
  else if (s < 3472) { base = c2; g = 24; cell = s - 2896; }
  else if (s < 3728) { base = c3; g = 16; cell = s - 3472; }
  else               { base = c4; g = 12; cell = s - 3728; }
  int i = cell / g, j = cell - i * g;
  const float* ch = base + c * g * g;
  float x = ch[i * g + j];
  float m = x;
  if (i > 0 && j > 0) m = fmaxf(m, ch[(i - 1) * g + j - 1]);
  if (i > 0)          m = fmaxf(m, ch[(i - 1) * g + j]);
  if (j > 0)          m = fmaxf(m, ch[i * g + j - 1]);
  // sigmoid strictly monotone+injective (fp64) on fp32 logits: compare logits directly.
  bool pass = (x >= m) && ((double)x > -2.1972245773362196 /* ln(1/9) */);
  flat[idx] = pass ? x : __int_as_float(0xFF800000);  // -inf sentinel
  if (pass) atomicAdd(&hist[fkey(x) >> 16], 1u);
}

// ---------- K2: pivot bucket so that count(>= pivot) >= 500 ----------
__global__ void k_pivot(const unsigned* __restrict__ hist, unsigned* __restrict__ meta) {
  __shared__ unsigned csum[1024];
  int t = threadIdx.x;
  int hi = 65536 - t * 64, lo = hi - 64;
  unsigned s = 0;
  for (int b = lo; b < hi; ++b) s += hist[b];
  csum[t] = s;
  __syncthreads();
  if (t == 0) {
    unsigned cum = 0;
    for (int cch = 0; cch < 1024; ++cch) {
      if (cum + csum[cch] >= NPRE) {
        int chi = 65536 - cch * 64;
        for (int b = chi - 1; b >= chi - 64; --b) {
          if (cum + hist[b] >= NPRE) { meta[1] = (unsigned)b; return; }
          cum += hist[b];
        }
      }
      cum += csum[cch];
    }
    meta[1] = 0u;  // fewer than 500 positives: take all (compact filters -inf)
  }
}

// ---------- K3: compact candidates (fp32 logit, index) ----------
__global__ __launch_bounds__(256) void k_compact(
    const float* __restrict__ flat, float* __restrict__ cv, int* __restrict__ ci,
    unsigned* __restrict__ meta) {
  int idx = blockIdx.x * 256 + threadIdx.x;
  if (idx >= NFLAT) return;
  float v = flat[idx];
  if (__float_as_uint(v) == 0xFF800000u) return;  // -inf sentinel
  if ((fkey(v) >> 16) >= meta[1]) {
    unsigned pos = atomicAdd(&meta[0], 1u);
    if (pos < 4096u) { cv[pos] = v; ci[pos] = idx; }
  }
}

// ---------- K4: exact (logit,idx) bitonic sort, take top-500; fp64 sigmoid for winners ----------
__global__ __launch_bounds__(1024) void k_select(
    const float* __restrict__ cv, const int* __restrict__ ci, const unsigned* __restrict__ meta,
    double* __restrict__ sel_score, unsigned* __restrict__ sel_grid,
    unsigned* __restrict__ sel_label, double* __restrict__ sel_stride) {
  __shared__ float sv[4096];
  __shared__ int si[4096];
  int t = threadIdx.x;
  int n = (meta[0] < 4096u) ? (int)meta[0] : 4096;
  for (int i = t; i < 4096; i += 1024) {
    if (i < n) { sv[i] = cv[i]; si[i] = ci[i]; }
    else       { sv[i] = __int_as_float(0xFF800000); si[i] = (1 << 30) + i; }
  }
  __syncthreads();
  for (int k = 2; k <= 4096; k <<= 1)
    for (int j = k >> 1; j > 0; j >>= 1) {
      for (int i = t; i < 4096; i += 1024) {
        int ix = i ^ j;
        if (ix > i) {
          float v1 = sv[i], v2 = sv[ix]; int i1 = si[i], i2 = si[ix];
          bool b2 = (v2 > v1) || (v2 == v1 && i2 < i1);  // entry ix ranks before entry i
          bool dir = (i & k) == 0;
          if (dir == b2) { sv[i] = v2; sv[ix] = v1; si[i] = i2; si[ix] = i1; }
        }
      }
      __syncthreads();
    }
  for (int i = t; i < NPREP; i += 1024) {
    if (i < NPRE && i < n) {
      int fidx = si[i];
      unsigned gi = (unsigned)fidx / NCLS;
      sel_score[i] = 1.0 / (1.0 + exp(-(double)sv[i]));
      sel_grid[i] = gi;
      sel_label[i] = (unsigned)fidx - gi * NCLS;
      sel_stride[i] = gi < 2896u ? 8.0 : (gi < 3472u ? 16.0 : 32.0);
    } else {
      sel_score[i] = 0.0; sel_grid[i] = 0u; sel_label[i] = 0u; sel_stride[i] = 1e18;
    }
  }
}

// ---------- K5: gather kernel vectors transposed kpT[k][n] ----------
__global__ __launch_bounds__(256) void k_gather(
    const float* __restrict__ k0, const float* __restrict__ k1, const float* __restrict__ k2,
    const float* __restrict__ k3, const float* __restrict__ k4,
    const unsigned* __restrict__ sel_grid, float* __restrict__ kpT) {
  int tid = blockIdx.x * 256 + threadIdx.x;
  if (tid >= NPREP * NKER) return;
  int n = tid & (NPREP - 1);
  int k = tid >> 9;
  float v = 0.f;
  if (n < NPRE) {
    unsigned gi = sel_grid[n];
    const float* base; unsigned g, cell;
    if (gi < 1600u)      { base = k0; g = 40; cell = gi; }
    else if (gi < 2896u) { base = k1; g = 36; cell = gi - 1600u; }
    else if (gi < 3472u) { base = k2; g = 24; cell = gi - 2896u; }
    else if (gi < 3728u) { base = k3; g = 16; cell = gi - 3472u; }
    else                 { base = k4; g = 12; cell = gi - 3728u; }
    v = base[(unsigned)k * g * g + cell];
  }
  kpT[k * NPREP + n] = v;
}

// ---------- K6: fp32-LDS / fp64-accumulate GEMM + fused epilogue ----------
// 64n x 128p tile, 256 threads, micro 4n x (4+4)p. LDS 48KB -> 3 blocks/CU.
__global__ __launch_bounds__(256, 3) void k_gemm(
    const float* __restrict__ kpT, const float* __restrict__ mf,
    unsigned short* __restrict__ seg, unsigned long long* __restrict__ mb,
    double* __restrict__ part) {
  __shared__ float As[BK][BN];   // 16KB  [k][n]
  __shared__ float Bs[BK][BP];   // 32KB  [k][p]
  int p0 = blockIdx.x * BP, n0 = blockIdx.y * BN;
  int tid = threadIdx.x;
  int tp = tid & 15, tn = tid >> 4;
  double acc[4][8] = {};
  for (int kc = 0; kc < NKER; kc += BK) {
    for (int q = tid; q < BK * 16; q += 256) {       // As: 64 rows x 16 float4
      int row = q >> 4, c4 = (q & 15) << 2;
      *(float4*)&As[row][c4] = *(const float4*)&kpT[(kc + row) * NPREP + n0 + c4];
    }
    for (int q = tid; q < BK * 32; q += 256) {       // Bs: 64 rows x 32 float4
      int row = q >> 5, c4 = (q & 31) << 2;
      *(float4*)&Bs[row][c4] = *(const float4*)&mf[(size_t)(kc + row) * MP + p0 + c4];
    }
    __syncthreads();
#pragma unroll 4
    for (int k = 0; k < BK; ++k) {
      float4 af = *(float4*)&As[k][tn << 2];                 // broadcast (4 addrs/wave)
      float4 b0 = *(float4*)&Bs[k][tp << 2];                 // 2-way -> free
      float4 b1 = *(float4*)&Bs[k][64 + (tp << 2)];          // 2-way -> free
      double a[4] = {af.x, af.y, af.z, af.w};
      double b[8] = {b0.x, b0.y, b0.z, b0.w, b1.x, b1.y, b1.z, b1.w};
#pragma unroll
      for (int r = 0; r < 4; ++r)
#pragma unroll
        for (int c = 0; c < 8; ++c)
          acc[r][c] = fma(a[r], b[c], acc[r][c]);
    }
    __syncthreads();
  }
  // epilogue: bit = (z>0) exact; seg/wsum via fp32 sigmoid (decision-safe), fp64 accum
  double* partL = (double*)&As[0][0];                         // [64][16] f64 (8KB)
  unsigned* nibL = (unsigned*)((char*)&As[0][0] + 8192);      // [64][16] u32 (4KB)
  for (int r = 0; r < 4; ++r) {
    int nl = (tn << 2) + r;
    int nn = n0 + nl;
    unsigned nb = 0; double wsum = 0.0;
    unsigned short u[8];
#pragma unroll
    for (int c = 0; c < 8; ++c) {
      float z = (float)acc[r][c];
      float sf = 1.0f / (1.0f + __expf(-z));
      u[c] = f2bf(sf);
      if (acc[r][c] > 0.0) { nb |= 1u << c; wsum += (double)sf; }
    }
    if (nn < NPRE) {
      ushort4 o0; o0.x = u[0]; o0.y = u[1]; o0.z = u[2]; o0.w = u[3];
      ushort4 o1; o1.x = u[4]; o1.y = u[5]; o1.z = u[6]; o1.w = u[7];
      *(ushort4*)&seg[(size_t)nn * MP + p0 + (tp << 2)] = o0;
      *(ushort4*)&seg[(size_t)nn * MP + p0 + 64 + (tp << 2)] = o1;
    }
    partL[nl * 16 + tp] = wsum;
    nibL[nl * 16 + tp] = nb;
  }
  __syncthreads();
  if (tid < 64) {
    int nn = n0 + tid;
    if (nn < NPRE) {
      double ssum = 0.0; unsigned long long w0 = 0ull, w1 = 0ull;
#pragma unroll
      for (int c = 0; c < 16; ++c) {
        ssum += partL[tid * 16 + c];
        unsigned nb = nibL[tid * 16 + c];
        w0 |= (unsigned long long)(nb & 0xFu) << (c << 2);
        w1 |= (unsigned long long)(nb >> 4) << (c << 2);
      }
      int bx = blockIdx.x;
      part[nn * PARTW + bx] = ssum;
      mb[nn * NWORD + bx * 2] = w0;
      mb[nn * NWORD + bx * 2 + 1] = w1;
    }
  }
}

// ---------- K7: per-instance reduce (exact count + fp64 weighted sum) -> updated score ----------
__global__ void k_masks(const unsigned long long* __restrict__ mb, const double* __restrict__ part,
                        const double* __restrict__ sel_score, const double* __restrict__ sel_stride,
                        double* __restrict__ summask, double* __restrict__ upd) {
  int n = blockIdx.x, t = threadIdx.x;
  int cnt = 0; double ws = 0.0;
  for (int j = t; j < NWORD; j += 64) cnt += __popcll(mb[n * NWORD + j]);
  for (int j = t; j < PARTW; j += 64) ws += part[n * PARTW + j];
  for (int o = 32; o > 0; o >>= 1) { cnt += __shfl_down(cnt, o); ws += __shfl_down(ws, o); }
  if (t == 0) {
    double cf = (double)cnt;
    double ss = ws / fmax(cf, 1.0);
    double raw = sel_score[n];
    bool keep = (cf > sel_stride[n]) && (raw > 0.0);
    summask[n] = cf;
    upd[n] = keep ? raw * ss : 0.0;
  }
}

// ---------- K8: stable descending fp64 sort of updated scores ----------
__global__ __launch_bounds__(512) void k_sort(
    const double* __restrict__ upd, const unsigned* __restrict__ sel_label, const double* __restrict__ summask,
    double* __restrict__ s_score, unsigned* __restrict__ s_slot, unsigned* __restrict__ s_label2,
    double* __restrict__ s_sum, unsigned* __restrict__ s_alive) {
  __shared__ double sv[NPREP];
  __shared__ int si[NPREP];
  int t = threadIdx.x;
  sv[t] = (t < NPRE) ? upd[t] : -1.0;
  si[t] = t;
  __syncthreads();
  for (int k = 2; k <= NPREP; k <<= 1)
    for (int j = k >> 1; j > 0; j >>= 1) {
      int ix = t ^ j;
      if (ix > t) {
        double v1 = sv[t], v2 = sv[ix]; int i1 = si[t], i2 = si[ix];
        bool b2 = (v2 > v1) || (v2 == v1 && i2 < i1);
        bool dir = (t & k) == 0;
        if (dir == b2) { sv[t] = v2; sv[ix] = v1; si[t] = i2; si[ix] = i1; }
      }
      __syncthreads();
    }
  double sc = sv[t]; int slot = si[t];
  bool alive = sc > 0.0;
  s_score[t] = alive ? sc : 0.0;
  s_slot[t] = (unsigned)slot;
  s_label2[t] = sel_label[slot];
  s_sum[t] = (alive && slot < NPRE) ? summask[slot] : 0.0;
  s_alive[t] = alive ? 1u : 0u;
}

// ---------- K9: pairwise IoU via popcount (exact), fp64 ----------
__global__ __launch_bounds__(256) void k_inter(
    const unsigned long long* __restrict__ mb, const unsigned* __restrict__ s_slot,
    const unsigned* __restrict__ s_label2, const unsigned* __restrict__ s_alive,
    const double* __restrict__ s_sum, double* __restrict__ iou) {
  int w = (blockIdx.x * 256 + threadIdx.x) >> 6;
  int lane = threadIdx.x & 63;
  if (w >= NPRE * NPRE) return;
  int i = w / NPRE, j = w - i * NPRE;
  if (i >= j) return;
  if (s_label2[i] != s_label2[j] || !s_alive[i] || !s_alive[j]) return;
  const unsigned long long* A = mb + (size_t)s_slot[i] * NWORD;
  const unsigned long long* B = mb + (size_t)s_slot[j] * NWORD;
  int c = 0;
  for (int wd = lane; wd < NWORD; wd += 64) c += __popcll(A[wd] & B[wd]);
  for (int o = 32; o > 0; o >>= 1) c += __shfl_down(c, o);
  if (lane == 0) {
    double inter = (double)c;
    double uni = s_sum[i] + s_sum[j] - inter;
    iou[i * NPRE + j] = (uni > 0.0) ? inter / fmax(uni, 1.0) : 0.0;
  }
}

// ---------- K10: matrix-NMS decay (fp64) + 0.05 threshold ----------
__global__ __launch_bounds__(512) void k_nms(const double* __restrict__ iou,
                                             const double* __restrict__ s_score,
                                             double* __restrict__ final_) {
  __shared__ double compS[NPREP];
  int t = threadIdx.x;
  double cm = 0.0;
  if (t < NPRE)
    for (int i = 0; i < t; ++i) cm = fmax(cm, iou[i * NPRE + t]);
  compS[t] = cm;
  __syncthreads();
  if (t < NPRE) {
    double m = 0.0;
    for (int i = 0; i < t; ++i) {
      double d = iou[i * NPRE + t];
      m = fmax(m, d * d - compS[i] * compS[i]);
    }
    double f = s_score[t] * exp(-2.0 * m);
    final_[t] = (f >= 0.05) ? f : 0.0;
  } else {
    final_[t] = 0.0;
  }
}

// ---------- K11: final stable top-100 ----------
__global__ __launch_bounds__(512) void k_top100(
    const double* __restrict__ final_, const unsigned* __restrict__ s_label2,
    const unsigned* __restrict__ s_slot, float* __restrict__ d_out, int maskN,
    unsigned* __restrict__ up_slot) {
  __shared__ double sv[NPREP];
  __shared__ int si[NPREP];
  int t = threadIdx.x;
  sv[t] = final_[t]; si[t] = t;
  __syncthreads();
  for (int k = 2; k <= NPREP; k <<= 1)
    for (int j = k >> 1; j > 0; j >>= 1) {
      int ix = t ^ j;
      if (ix > t) {
        double v1 = sv[t], v2 = sv[ix]; int i1 = si[t], i2 = si[ix];
        bool b2 = (v2 > v1) || (v2 == v1 && i2 < i1);
        bool dir = (t & k) == 0;
        if (dir == b2) { sv[t] = v2; sv[ix] = v1; si[t] = i2; si[ix] = i1; }
      }
      __syncthreads();
    }
  if (t < MAXI) {
    int pos = si[t];
    d_out[maskN + t] = (float)sv[t];
    d_out[maskN + MAXI + t] = (float)s_label2[pos];
    up_slot[t] = s_slot[pos];
  }
}

// ---------- K12: 4x bilinear upsample (bf16 seg) + threshold ----------
__global__ __launch_bounds__(256) void k_up(const unsigned short* __restrict__ seg,
                                            const unsigned* __restrict__ up_slot,
                                            float* __restrict__ out, int maskN) {
  int o = blockIdx.x * 256 + threadIdx.x;
  if (o >= maskN) return;
  int m = o / (OH * OW);
  int rem = o - m * (OH * OW);
  int y = rem / OW, x = rem - y * OW;
  const unsigned short* row = seg + (size_t)up_slot[m] * MP;
  float sy = y * 0.25f - 0.375f, sx = x * 0.25f - 0.375f;
  int y0 = (int)floorf(sy), x0 = (int)floorf(sx);
  float wy = sy - y0, wx = sx - x0;
  int y0c = max(y0, 0), y1c = min(y0 + 1, MH - 1);
  int x0c = max(x0, 0), x1c = min(x0 + 1, MW - 1);
  float s00 = bf2f(row[y0c * MW + x0c]), s01 = bf2f(row[y0c * MW + x1c]);
  float s10 = bf2f(row[y1c * MW + x0c]), s11 = bf2f(row[y1c * MW + x1c]);
  float v = (1.f - wy) * ((1.f - wx) * s00 + wx * s01) + wy * ((1.f - wx) * s10 + wx * s11);
  out[o] = (v > 0.5f) ? 1.f : 0.f;
}

extern "C" void kernel_launch(void* const* d_in, const int* in_sizes, int n_in,
                              void* d_out, int out_size, void* d_ws, size_t ws_size,
                              hipStream_t stream) {
  // setup_inputs() dict order is INTERLEAVED: cate_p0, kern_p0, cate_p1, kern_p1, ...
  const float* c0 = (const float*)d_in[0];
  const float* k0 = (const float*)d_in[1];
  const float* c1 = (const float*)d_in[2];
  const float* k1 = (const float*)d_in[3];
  const float* c2 = (const float*)d_in[4];
  const float* k2 = (const float*)d_in[5];
  const float* c3 = (const float*)d_in[6];
  const float* k3 = (const float*)d_in[7];
  const float* c4 = (const float*)d_in[8];
  const float* k4 = (const float*)d_in[9];
  const float* mf = (const float*)d_in[10];

  char* ws = (char*)d_ws;
  unsigned* hist = (unsigned*)(ws + WS_HIST);
  unsigned* meta = (unsigned*)(ws + WS_META);
  double* iou = (double*)(ws + WS_IOU);
  float* flat = (float*)(ws + WS_FLAT);
  float* cv = (float*)(ws + WS_CANDV);
  int* ci = (int*)(ws + WS_CANDI);
  double* sel_score  = (double*)(ws + WS_SEL + 0);
  unsigned* sel_grid = (unsigned*)(ws + WS_SEL + 4096);
  unsigned* sel_label= (unsigned*)(ws + WS_SEL + 8192);
  double* sel_stride = (double*)(ws + WS_SEL + 12288);
  double* upd        = (double*)(ws + WS_SEL + 16384);
  double* summask    = (double*)(ws + WS_SEL + 20480);
  double* s_score    = (double*)(ws + WS_SEL + 24576);
  unsigned* s_slot   = (unsigned*)(ws + WS_SEL + 28672);
  unsigned* s_label2 = (unsigned*)(ws + WS_SEL + 32768);
  double* s_sum      = (double*)(ws + WS_SEL + 36864);
  unsigned* s_alive  = (unsigned*)(ws + WS_SEL + 40960);
  double* final_     = (double*)(ws + WS_SEL + 45056);
  unsigned* up_slot  = (unsigned*)(ws + WS_SEL + 49152);
  float* kpT = (float*)(ws + WS_KPT);
  unsigned long long* mb = (unsigned long long*)(ws + WS_MB);
  double* part = (double*)(ws + WS_PART);
  unsigned short* seg = (unsigned short*)(ws + WS_SEG);

  int maskN = out_size - 2 * MAXI;  // 100*640*960

  hipMemsetAsync(ws, 0, WS_ZEROB, stream);  // hist + meta + iou

  k_flat<<<(NFLAT + 255) / 256, 256, 0, stream>>>(c0, c1, c2, c3, c4, flat, hist);
  k_pivot<<<1, 1024, 0, stream>>>(hist, meta);
  k_compact<<<(NFLAT + 255) / 256, 256, 0, stream>>>(flat, cv, ci, meta);
  k_select<<<1, 1024, 0, stream>>>(cv, ci, meta, sel_score, sel_grid, sel_label, sel_stride);
  k_gather<<<(NPREP * NKER + 255) / 256, 256, 0, stream>>>(k0, k1, k2, k3, k4, sel_grid, kpT);
  dim3 g6(MP / BP, NPREP / BN);  // 300 x 8
  k_gemm<<<g6, 256, 0, stream>>>(kpT, mf, seg, mb, part);
  k_masks<<<NPRE, 64, 0, stream>>>(mb, part, sel_score, sel_stride, summask, upd);
  k_sort<<<1, NPREP, 0, stream>>>(upd, sel_label, summask, s_score, s_slot, s_label2, s_sum, s_alive);
  k_inter<<<(NPRE * NPRE) / 4, 256, 0, stream>>>(mb, s_slot, s_label2, s_alive, s_sum, iou);
  k_nms<<<1, NPREP, 0, stream>>>(iou, s_score, final_);
  k_top100<<<1, NPREP, 0, stream>>>(final_, s_label2, s_slot, (float*)d_out, maskN, up_slot);
  k_up<<<(maskN + 255) / 256, 256, 0, stream>>>(seg, up_slot, (float*)d_out, maskN);
}

// Round 5
// 671.194 us; speedup vs baseline: 1.3027x; 1.0796x over previous
//
#include <hip/hip_runtime.h>
#include <stdint.h>

#define NCLS 80
#define NKER 256
#define STOT 3872
#define NFLAT (STOT*NCLS)   // 309760
#define NPRE 500
#define NPREP 512
#define MAXI 100
#define MH 160
#define MW 240
#define MP (MH*MW)          // 38400
#define OH 640
#define OW 960
#define NWORD 600           // 38400/64
#define PARTW 300           // 38400/128

// GEMM tiling
#define BN 64
#define BP 128
#define BK 32

// ---- workspace byte offsets ----
#define WS_HIST   0u          // 65536 u32 = 262144
#define WS_META   262144u
#define WS_ZEROB  266240u     // memset range [0, WS_ZEROB): hist + meta only
#define WS_IOU    266240u     // 500*500 f64 = 2,000,000 (fully written by k_inter)
#define WS_FLAT   2266240u    // 309760 f32 = 1,239,040
#define WS_CANDV  3505280u    // 4096 f32
#define WS_CANDI  3521664u    // 4096 i32
#define WS_SEL    3538048u    // 13 arrays x 4096B
#define WS_KPT    3591296u    // 256*512 f32 = 524,288
#define WS_MB     4115584u    // 500*600 u64 = 2,400,000
#define WS_PART   6515584u    // 500*300 f64 = 1,200,000
#define WS_SEG    7715584u    // 500*38400 u16 (bf16) -> ends ~46.1MB

__device__ __forceinline__ float bf2f(unsigned short u) { return __uint_as_float(((unsigned)u) << 16); }
__device__ __forceinline__ unsigned short f2bf(float f) {
  unsigned b = __float_as_uint(f);
  return (unsigned short)((b + 0x7fffu + ((b >> 16) & 1u)) >> 16);
}
// monotone float->uint key (total order matching <)
__device__ __forceinline__ unsigned fkey(float f) {
  unsigned b = __float_as_uint(f);
  return b ^ ((b & 0x80000000u) ? 0xFFFFFFFFu : 0x80000000u);
}

// ---------- K1: point-NMS + threshold in LOGIT space (exact-equivalent, no exp) ----------
__global__ __launch_bounds__(256) void k_flat(
    const float* __restrict__ c0, const float* __restrict__ c1, const float* __restrict__ c2,
    const float* __restrict__ c3, const float* __restrict__ c4,
    float* __restrict__ flat, unsigned* __restrict__ hist) {
  int idx = blockIdx.x * 256 + threadIdx.x;
  if (idx >= NFLAT) return;
  int s = idx / NCLS, c = idx - s * NCLS;
  const float* base; int g, cell;
  if (s < 1600)      { base = c0; g = 40; cell = s; }
  else if (s < 2896) { base = c1; g = 36; cell = s - 1600; }
  else if (s < 3472) { base = c2; g = 24; cell = s - 2896; }
  else if (s < 3728) { base = c3; g = 16; cell = s - 3472; }
  else               { base = c4; g = 12; cell = s - 3728; }
  int i = cell / g, j = cell - i * g;
  const float* ch = base + c * g * g;
  float x = ch[i * g + j];
  float m = x;
  if (i > 0 && j > 0) m = fmaxf(m, ch[(i - 1) * g + j - 1]);
  if (i > 0)          m = fmaxf(m, ch[(i - 1) * g + j]);
  if (j > 0)          m = fmaxf(m, ch[i * g + j - 1]);
  // sigmoid strictly monotone+injective (fp64) on fp32 logits: compare logits directly.
  bool pass = (x >= m) && ((double)x > -2.1972245773362196 /* ln(1/9) */);
  flat[idx] = pass ? x : __int_as_float(0xFF800000);  // -inf sentinel
  if (pass) atomicAdd(&hist[fkey(x) >> 16], 1u);
}

// ---------- K2: pivot bucket so that count(>= pivot) >= 500 ----------
__global__ void k_pivot(const unsigned* __restrict__ hist, unsigned* __restrict__ meta) {
  __shared__ unsigned csum[1024];
  int t = threadIdx.x;
  int hi = 65536 - t * 64, lo = hi - 64;
  unsigned s = 0;
  for (int b = lo; b < hi; ++b) s += hist[b];
  csum[t] = s;
  __syncthreads();
  if (t == 0) {
    unsigned cum = 0;
    for (int cch = 0; cch < 1024; ++cch) {
      if (cum + csum[cch] >= NPRE) {
        int chi = 65536 - cch * 64;
        for (int b = chi - 1; b >= chi - 64; --b) {
          if (cum + hist[b] >= NPRE) { meta[1] = (unsigned)b; return; }
          cum += hist[b];
        }
      }
      cum += csum[cch];
    }
    meta[1] = 0u;  // fewer than 500 positives: take all (compact filters -inf)
  }
}

// ---------- K3: compact candidates (fp32 logit, index) ----------
__global__ __launch_bounds__(256) void k_compact(
    const float* __restrict__ flat, float* __restrict__ cv, int* __restrict__ ci,
    unsigned* __restrict__ meta) {
  int idx = blockIdx.x * 256 + threadIdx.x;
  if (idx >= NFLAT) return;
  float v = flat[idx];
  if (__float_as_uint(v) == 0xFF800000u) return;  // -inf sentinel
  if ((fkey(v) >> 16) >= meta[1]) {
    unsigned pos = atomicAdd(&meta[0], 1u);
    if (pos < 4096u) { cv[pos] = v; ci[pos] = idx; }
  }
}

// ---------- K4: exact (logit,idx) bitonic sort, take top-500; fp64 sigmoid for winners ----------
__global__ __launch_bounds__(1024) void k_select(
    const float* __restrict__ cv, const int* __restrict__ ci, const unsigned* __restrict__ meta,
    double* __restrict__ sel_score, unsigned* __restrict__ sel_grid,
    unsigned* __restrict__ sel_label, double* __restrict__ sel_stride) {
  __shared__ float sv[4096];
  __shared__ int si[4096];
  int t = threadIdx.x;
  int n = (meta[0] < 4096u) ? (int)meta[0] : 4096;
  for (int i = t; i < 4096; i += 1024) {
    if (i < n) { sv[i] = cv[i]; si[i] = ci[i]; }
    else       { sv[i] = __int_as_float(0xFF800000); si[i] = (1 << 30) + i; }
  }
  __syncthreads();
  for (int k = 2; k <= 4096; k <<= 1)
    for (int j = k >> 1; j > 0; j >>= 1) {
      for (int i = t; i < 4096; i += 1024) {
        int ix = i ^ j;
        if (ix > i) {
          float v1 = sv[i], v2 = sv[ix]; int i1 = si[i], i2 = si[ix];
          bool b2 = (v2 > v1) || (v2 == v1 && i2 < i1);  // entry ix ranks before entry i
          bool dir = (i & k) == 0;
          if (dir == b2) { sv[i] = v2; sv[ix] = v1; si[i] = i2; si[ix] = i1; }
        }
      }
      __syncthreads();
    }
  for (int i = t; i < NPREP; i += 1024) {
    if (i < NPRE && i < n) {
      int fidx = si[i];
      unsigned gi = (unsigned)fidx / NCLS;
      sel_score[i] = 1.0 / (1.0 + exp(-(double)sv[i]));
      sel_grid[i] = gi;
      sel_label[i] = (unsigned)fidx - gi * NCLS;
      sel_stride[i] = gi < 2896u ? 8.0 : (gi < 3472u ? 16.0 : 32.0);
    } else {
      sel_score[i] = 0.0; sel_grid[i] = 0u; sel_label[i] = 0u; sel_stride[i] = 1e18;
    }
  }
}

// ---------- K5: gather kernel vectors transposed kpT[k][n] ----------
__global__ __launch_bounds__(256) void k_gather(
    const float* __restrict__ k0, const float* __restrict__ k1, const float* __restrict__ k2,
    const float* __restrict__ k3, const float* __restrict__ k4,
    const unsigned* __restrict__ sel_grid, float* __restrict__ kpT) {
  int tid = blockIdx.x * 256 + threadIdx.x;
  if (tid >= NPREP * NKER) return;
  int n = tid & (NPREP - 1);
  int k = tid >> 9;
  float v = 0.f;
  if (n < NPRE) {
    unsigned gi = sel_grid[n];
    const float* base; unsigned g, cell;
    if (gi < 1600u)      { base = k0; g = 40; cell = gi; }
    else if (gi < 2896u) { base = k1; g = 36; cell = gi - 1600u; }
    else if (gi < 3472u) { base = k2; g = 24; cell = gi - 2896u; }
    else if (gi < 3728u) { base = k3; g = 16; cell = gi - 3472u; }
    else                 { base = k4; g = 12; cell = gi - 3728u; }
    v = base[(unsigned)k * g * g + cell];
  }
  kpT[k * NPREP + n] = v;
}

// ---------- K6: fp64 GEMM, f64 staged in LDS (zero cvt in inner loop) + fused epilogue ----------
// 64n x 128p tile, BK=32, 256 threads, micro 4n x 8p. LDS 48KB -> 3 blocks/CU.
// acc fma sequence identical (k ascending over identical f64-converted values) to prior rounds.
__global__ __launch_bounds__(256, 3) void k_gemm(
    const float* __restrict__ kpT, const float* __restrict__ mf,
    unsigned short* __restrict__ seg, unsigned long long* __restrict__ mb,
    double* __restrict__ part) {
  __shared__ double Asd[BK][BN];   // 16KB  [k][n]
  __shared__ double Bsd[BK][BP];   // 32KB  [k][p]
  int p0 = blockIdx.x * BP, n0 = blockIdx.y * BN;
  int tid = threadIdx.x;
  int tp = tid & 15, tn = tid >> 4;
  double acc[4][8] = {};
  for (int kc = 0; kc < NKER; kc += BK) {
#pragma unroll
    for (int it = 0; it < 4; ++it) {              // A: 1024 float2 total
      int q = it * 256 + tid;
      int row = q >> 5, c2 = q & 31;
      float2 f = *(const float2*)&kpT[(kc + row) * NPREP + n0 + c2 * 2];
      double2 d; d.x = (double)f.x; d.y = (double)f.y;
      *(double2*)&Asd[row][c2 * 2] = d;
    }
#pragma unroll
    for (int it = 0; it < 8; ++it) {              // B: 2048 float2 total
      int q = it * 256 + tid;
      int row = q >> 6, c2 = q & 63;
      float2 f = *(const float2*)&mf[(size_t)(kc + row) * MP + p0 + c2 * 2];
      double2 d; d.x = (double)f.x; d.y = (double)f.y;
      *(double2*)&Bsd[row][c2 * 2] = d;
    }
    __syncthreads();
#pragma unroll 4
    for (int k = 0; k < BK; ++k) {
      double2 a01 = *(double2*)&Asd[k][(tn << 2)];
      double2 a23 = *(double2*)&Asd[k][(tn << 2) + 2];
      double2 b0 = *(double2*)&Bsd[k][tp * 2];
      double2 b1 = *(double2*)&Bsd[k][32 + tp * 2];
      double2 b2 = *(double2*)&Bsd[k][64 + tp * 2];
      double2 b3 = *(double2*)&Bsd[k][96 + tp * 2];
      double a[4] = {a01.x, a01.y, a23.x, a23.y};
      double b[8] = {b0.x, b0.y, b1.x, b1.y, b2.x, b2.y, b3.x, b3.y};
#pragma unroll
      for (int r = 0; r < 4; ++r)
#pragma unroll
        for (int c = 0; c < 8; ++c)
          acc[r][c] = fma(a[r], b[c], acc[r][c]);
    }
    __syncthreads();
  }
  // thread's p positions: c=(g,b): p = p0 + g*32 + tp*2 + b,  g=c>>1, b=c&1
  double* partL = (double*)&Asd[0][0];                        // [64][16] f64 (8KB)
  unsigned* nibL = (unsigned*)((char*)&Asd[0][0] + 8192);     // [64][16] u32 (4KB)
  for (int r = 0; r < 4; ++r) {
    int nl = (tn << 2) + r;
    int nn = n0 + nl;
    unsigned nb = 0; double wsum = 0.0;
    unsigned short u[8];
#pragma unroll
    for (int c = 0; c < 8; ++c) {
      float z = (float)acc[r][c];
      float sf = 1.0f / (1.0f + __expf(-z));
      u[c] = f2bf(sf);
      if (acc[r][c] > 0.0) { nb |= 1u << c; wsum += (double)sf; }
    }
    if (nn < NPRE) {
#pragma unroll
      for (int g = 0; g < 4; ++g) {
        ushort2 o; o.x = u[2 * g]; o.y = u[2 * g + 1];
        *(ushort2*)&seg[(size_t)nn * MP + p0 + g * 32 + tp * 2] = o;
      }
    }
    partL[nl * 16 + tp] = wsum;
    nibL[nl * 16 + tp] = nb;
  }
  __syncthreads();
  if (tid < 64) {
    int nn = n0 + tid;
    if (nn < NPRE) {
      double ssum = 0.0; unsigned long long w0 = 0ull, w1 = 0ull;
#pragma unroll
      for (int c = 0; c < 16; ++c) {
        ssum += partL[tid * 16 + c];
        unsigned long long nb = (unsigned long long)nibL[tid * 16 + c];
        w0 |= ((nb      & 3ull) << (c * 2)) | (((nb >> 2) & 3ull) << (32 + c * 2));
        w1 |= (((nb >> 4) & 3ull) << (c * 2)) | (((nb >> 6) & 3ull) << (32 + c * 2));
      }
      int bx = blockIdx.x;
      part[nn * PARTW + bx] = ssum;
      mb[nn * NWORD + bx * 2] = w0;
      mb[nn * NWORD + bx * 2 + 1] = w1;
    }
  }
}

// ---------- K7: per-instance reduce (exact count + fp64 weighted sum) -> updated score ----------
__global__ void k_masks(const unsigned long long* __restrict__ mb, const double* __restrict__ part,
                        const double* __restrict__ sel_score, const double* __restrict__ sel_stride,
                        double* __restrict__ summask, double* __restrict__ upd) {
  int n = blockIdx.x, t = threadIdx.x;
  int cnt = 0; double ws = 0.0;
  for (int j = t; j < NWORD; j += 64) cnt += __popcll(mb[n * NWORD + j]);
  for (int j = t; j < PARTW; j += 64) ws += part[n * PARTW + j];
  for (int o = 32; o > 0; o >>= 1) { cnt += __shfl_down(cnt, o); ws += __shfl_down(ws, o); }
  if (t == 0) {
    double cf = (double)cnt;
    double ss = ws / fmax(cf, 1.0);
    double raw = sel_score[n];
    bool keep = (cf > sel_stride[n]) && (raw > 0.0);
    summask[n] = cf;
    upd[n] = keep ? raw * ss : 0.0;
  }
}

// ---------- K8: stable descending fp64 sort of updated scores ----------
__global__ __launch_bounds__(512) void k_sort(
    const double* __restrict__ upd, const unsigned* __restrict__ sel_label, const double* __restrict__ summask,
    double* __restrict__ s_score, unsigned* __restrict__ s_slot, unsigned* __restrict__ s_label2,
    double* __restrict__ s_sum, unsigned* __restrict__ s_alive) {
  __shared__ double sv[NPREP];
  __shared__ int si[NPREP];
  int t = threadIdx.x;
  sv[t] = (t < NPRE) ? upd[t] : -1.0;
  si[t] = t;
  __syncthreads();
  for (int k = 2; k <= NPREP; k <<= 1)
    for (int j = k >> 1; j > 0; j >>= 1) {
      int ix = t ^ j;
      if (ix > t) {
        double v1 = sv[t], v2 = sv[ix]; int i1 = si[t], i2 = si[ix];
        bool b2 = (v2 > v1) || (v2 == v1 && i2 < i1);
        bool dir = (t & k) == 0;
        if (dir == b2) { sv[t] = v2; sv[ix] = v1; si[t] = i2; si[ix] = i1; }
      }
      __syncthreads();
    }
  double sc = sv[t]; int slot = si[t];
  bool alive = sc > 0.0;
  s_score[t] = alive ? sc : 0.0;
  s_slot[t] = (unsigned)slot;
  s_label2[t] = sel_label[slot];
  s_sum[t] = (alive && slot < NPRE) ? summask[slot] : 0.0;
  s_alive[t] = alive ? 1u : 0u;
}

// ---------- K9: pairwise IoU via popcount (exact), fp64; writes ALL i<j (no memset dep) ----------
__global__ __launch_bounds__(256) void k_inter(
    const unsigned long long* __restrict__ mb, const unsigned* __restrict__ s_slot,
    const unsigned* __restrict__ s_label2, const unsigned* __restrict__ s_alive,
    const double* __restrict__ s_sum, double* __restrict__ iou) {
  int w = (blockIdx.x * 256 + threadIdx.x) >> 6;
  int lane = threadIdx.x & 63;
  if (w >= NPRE * NPRE) return;
  int i = w / NPRE, j = w - i * NPRE;
  if (i >= j) return;
  double val = 0.0;
  if (s_label2[i] == s_label2[j] && s_alive[i] && s_alive[j]) {
    const unsigned long long* A = mb + (size_t)s_slot[i] * NWORD;
    const unsigned long long* B = mb + (size_t)s_slot[j] * NWORD;
    int c = 0;
    for (int wd = lane; wd < NWORD; wd += 64) c += __popcll(A[wd] & B[wd]);
    for (int o = 32; o > 0; o >>= 1) c += __shfl_down(c, o);
    double inter = (double)c;
    double uni = s_sum[i] + s_sum[j] - inter;
    val = (uni > 0.0) ? inter / fmax(uni, 1.0) : 0.0;
  }
  if (lane == 0) iou[i * NPRE + j] = val;
}

// ---------- K10: fused matrix-NMS decay + 0.05 threshold + stable top-100 ----------
__global__ __launch_bounds__(512) void k_nms_top(
    const double* __restrict__ iou, const double* __restrict__ s_score,
    const unsigned* __restrict__ s_label2, const unsigned* __restrict__ s_slot,
    float* __restrict__ d_out, int maskN, unsigned* __restrict__ up_slot) {
  __shared__ double compS[NPREP];
  __shared__ double sv[NPREP];
  __shared__ int si[NPREP];
  int t = threadIdx.x;
  double cm = 0.0;
  if (t < NPRE)
    for (int i = 0; i < t; ++i) cm = fmax(cm, iou[i * NPRE + t]);
  compS[t] = cm;
  __syncthreads();
  double f = 0.0;
  if (t < NPRE) {
    double m = 0.0;
    for (int i = 0; i < t; ++i) {
      double d = iou[i * NPRE + t];
      m = fmax(m, d * d - compS[i] * compS[i]);
    }
    f = s_score[t] * exp(-2.0 * m);
    if (f < 0.05) f = 0.0;
  }
  sv[t] = f; si[t] = t;
  __syncthreads();
  for (int k = 2; k <= NPREP; k <<= 1)
    for (int j = k >> 1; j > 0; j >>= 1) {
      int ix = t ^ j;
      if (ix > t) {
        double v1 = sv[t], v2 = sv[ix]; int i1 = si[t], i2 = si[ix];
        bool b2 = (v2 > v1) || (v2 == v1 && i2 < i1);
        bool dir = (t & k) == 0;
        if (dir == b2) { sv[t] = v2; sv[ix] = v1; si[t] = i2; si[ix] = i1; }
      }
      __syncthreads();
    }
  if (t < MAXI) {
    int pos = si[t];
    d_out[maskN + t] = (float)sv[t];
    d_out[maskN + MAXI + t] = (float)s_label2[pos];
    up_slot[t] = s_slot[pos];
  }
}

// ---------- K11: 4x bilinear upsample, 4 px/thread, float4 stores ----------
__global__ __launch_bounds__(256) void k_up(const unsigned short* __restrict__ seg,
                                            const unsigned* __restrict__ up_slot,
                                            float* __restrict__ out, int maskN) {
  int o4 = (blockIdx.x * 256 + threadIdx.x) * 4;
  if (o4 >= maskN) return;
  int m = o4 / (OH * OW);               // constant div -> mulhi
  int rem = o4 - m * (OH * OW);
  int y = rem / OW;
  int x = rem - y * OW;                 // multiple of 4, row-safe
  int a = x >> 2;
  const unsigned short* row = seg + (size_t)up_slot[m] * MP;
  float sy = y * 0.25f - 0.375f;
  int y0 = (int)floorf(sy);
  float wy = sy - y0;
  int y0c = max(y0, 0), y1c = min(y0 + 1, MH - 1);
  const unsigned short* r0 = row + y0c * MW;
  const unsigned short* r1 = row + y1c * MW;
  int t0 = max(a - 1, 0), t1 = a, t2 = min(a + 1, MW - 1);
  float T0 = bf2f(r0[t0]), T1 = bf2f(r0[t1]), T2 = bf2f(r0[t2]);
  float B0 = bf2f(r1[t0]), B1 = bf2f(r1[t1]), B2 = bf2f(r1[t2]);
  float iwy = 1.f - wy;
  float4 o;
  o.x = iwy * (0.375f * T0 + 0.625f * T1) + wy * (0.375f * B0 + 0.625f * B1);
  o.y = iwy * (0.125f * T0 + 0.875f * T1) + wy * (0.125f * B0 + 0.875f * B1);
  o.z = iwy * (0.875f * T1 + 0.125f * T2) + wy * (0.875f * B1 + 0.125f * B2);
  o.w = iwy * (0.625f * T1 + 0.375f * T2) + wy * (0.625f * B1 + 0.375f * B2);
  o.x = (o.x > 0.5f) ? 1.f : 0.f;
  o.y = (o.y > 0.5f) ? 1.f : 0.f;
  o.z = (o.z > 0.5f) ? 1.f : 0.f;
  o.w = (o.w > 0.5f) ? 1.f : 0.f;
  *(float4*)&out[o4] = o;
}

extern "C" void kernel_launch(void* const* d_in, const int* in_sizes, int n_in,
                              void* d_out, int out_size, void* d_ws, size_t ws_size,
                              hipStream_t stream) {
  // setup_inputs() dict order is INTERLEAVED: cate_p0, kern_p0, cate_p1, kern_p1, ...
  const float* c0 = (const float*)d_in[0];
  const float* k0 = (const float*)d_in[1];
  const float* c1 = (const float*)d_in[2];
  const float* k1 = (const float*)d_in[3];
  const float* c2 = (const float*)d_in[4];
  const float* k2 = (const float*)d_in[5];
  const float* c3 = (const float*)d_in[6];
  const float* k3 = (const float*)d_in[7];
  const float* c4 = (const float*)d_in[8];
  const float* k4 = (const float*)d_in[9];
  const float* mf = (const float*)d_in[10];

  char* ws = (char*)d_ws;
  unsigned* hist = (unsigned*)(ws + WS_HIST);
  unsigned* meta = (unsigned*)(ws + WS_META);
  double* iou = (double*)(ws + WS_IOU);
  float* flat = (float*)(ws + WS_FLAT);
  float* cv = (float*)(ws + WS_CANDV);
  int* ci = (int*)(ws + WS_CANDI);
  double* sel_score  = (double*)(ws + WS_SEL + 0);
  unsigned* sel_grid = (unsigned*)(ws + WS_SEL + 4096);
  unsigned* sel_label= (unsigned*)(ws + WS_SEL + 8192);
  double* sel_stride = (double*)(ws + WS_SEL + 12288);
  double* upd        = (double*)(ws + WS_SEL + 16384);
  double* summask    = (double*)(ws + WS_SEL + 20480);
  double* s_score    = (double*)(ws + WS_SEL + 24576);
  unsigned* s_slot   = (unsigned*)(ws + WS_SEL + 28672);
  unsigned* s_label2 = (unsigned*)(ws + WS_SEL + 32768);
  double* s_sum      = (double*)(ws + WS_SEL + 36864);
  unsigned* s_alive  = (unsigned*)(ws + WS_SEL + 40960);
  unsigned* up_slot  = (unsigned*)(ws + WS_SEL + 49152);
  float* kpT = (float*)(ws + WS_KPT);
  unsigned long long* mb = (unsigned long long*)(ws + WS_MB);
  double* part = (double*)(ws + WS_PART);
  unsigned short* seg = (unsigned short*)(ws + WS_SEG);

  int maskN = out_size - 2 * MAXI;  // 100*640*960

  hipMemsetAsync(ws, 0, WS_ZEROB, stream);  // hist + meta only

  k_flat<<<(NFLAT + 255) / 256, 256, 0, stream>>>(c0, c1, c2, c3, c4, flat, hist);
  k_pivot<<<1, 1024, 0, stream>>>(hist, meta);
  k_compact<<<(NFLAT + 255) / 256, 256, 0, stream>>>(flat, cv, ci, meta);
  k_select<<<1, 1024, 0, stream>>>(cv, ci, meta, sel_score, sel_grid, sel_label, sel_stride);
  k_gather<<<(NPREP * NKER + 255) / 256, 256, 0, stream>>>(k0, k1, k2, k3, k4, sel_grid, kpT);
  dim3 g6(MP / BP, NPREP / BN);  // 300 x 8
  k_gemm<<<g6, 256, 0, stream>>>(kpT, mf, seg, mb, part);
  k_masks<<<NPRE, 64, 0, stream>>>(mb, part, sel_score, sel_stride, summask, upd);
  k_sort<<<1, NPREP, 0, stream>>>(upd, sel_label, summask, s_score, s_slot, s_label2, s_sum, s_alive);
  k_inter<<<(NPRE * NPRE) / 4, 256, 0, stream>>>(mb, s_slot, s_label2, s_alive, s_sum, iou);
  k_nms_top<<<1, NPREP, 0, stream>>>(iou, s_score, s_label2, s_slot, (float*)d_out, maskN, up_slot);
  k_up<<<(maskN / 4 + 255) / 256, 256, 0, stream>>>(seg, up_slot, (float*)d_out, maskN);
}